// Round 4
// baseline (97.028 us; speedup 1.0000x reference)
//
#include <hip/hip_runtime.h>
#include <cstdint>
#include <utility>

#ifndef __has_builtin
#define __has_builtin(x) 0
#endif

// Extract bit `off` of x and sign-extend: returns 0 or -1 (all-ones mask).
__device__ __forceinline__ int sbfe1(unsigned x, int off) {
#if __has_builtin(__builtin_amdgcn_sbfe)
    return __builtin_amdgcn_sbfe((int)x, off, 1);
#else
    return ((int)(x << (31 - off))) >> 31;
#endif
}

// ---------------------------------------------------------------------------
// Compile-time mask table, built in 64 per-g chunks so each constexpr
// evaluation stays far under clang's -fconstexpr-steps limit (1M).
//
// Word layout for (t, g): 16 pairs (r,q), pi = r*4+q.
//   bit pi    : sign of gp term (1 = negative)
//   bit 16+pi : wedge condition (m subset of i)
//   bit 32+pi : inner condition (m&i==0 or i subset of m)
// where i = 4t+r, m = 4g+q, j = m^i.
// ---------------------------------------------------------------------------
struct Row { unsigned long long v[64]; };

constexpr Row build_row(int g) {
    Row row{};
    for (int t = 0; t < 64; ++t) {
        unsigned long long word = 0ull;
        for (int r = 0; r < 4; ++r) {
            for (int q = 0; q < 4; ++q) {
                const int i = 4 * t + r;
                const int m = 4 * g + q;
                const int j = m ^ i;
                const int pi = r * 4 + q;
                int cnt = 0, pb = 0;  // pb = popc(m & ((1<<p)-1))
                for (int p = 0; p < 8; ++p) {
                    if ((j >> p) & 1) cnt += pb;
                    pb += (m >> p) & 1;
                }
                if (cnt & 1)                           word |= (1ull << pi);
                if ((m & ~i) == 0)                     word |= (1ull << (16 + pi));
                if (((m & i) == 0) || ((i & ~m) == 0)) word |= (1ull << (32 + pi));
            }
        }
        row.v[t] = word;
    }
    return row;
}

template <int G>
inline constexpr Row row_v = build_row(G);  // one constexpr eval per g (~60K steps)

struct MaskTbl { unsigned long long v[4096]; };

constexpr void copy_row(MaskTbl& tb, int g, const Row& r) {
    for (int t = 0; t < 64; ++t) tb.v[g * 64 + t] = r.v[t];
}

template <std::size_t... Gs>
constexpr MaskTbl gather(std::index_sequence<Gs...>) {
    MaskTbl tb{};
    ((copy_row(tb, (int)Gs, row_v<(int)Gs>)), ...);  // reads cached constants only
    return tb;
}

// 32 KB static device table — no workspace, no prep kernel. L2-resident.
__device__ constexpr MaskTbl TBL = gather(std::make_index_sequence<64>{});

// 2 rows per block, 512 blocks, 512 threads: 2 blocks/CU = 4 waves/SIMD so
// independent blocks hide each other's LDS waits and barriers (at 1 block/CU
// the 2-waves/SIMD schedule exposed ~50% stall in the main loop).
// Scalar FP32 core (known-good codegen; the float2 pk attempt regressed).
__global__ __launch_bounds__(512) void clifford_main_kernel(
        const float* __restrict__ A, const float* __restrict__ B,
        float* __restrict__ out) {
    __shared__ float As[2][256];
    __shared__ float Bs[2][256];
    __shared__ unsigned long long masks[4096];  // 32 KB; reused as red[8][512]

    const int tid = threadIdx.x;   // 0..511
    const int r0 = blockIdx.x * 2; // rows r0, r0+1

    {
        const int row = tid >> 8;  // 0..1
        const int c = tid & 255;
        As[row][c] = A[(r0 + row) * 256 + c];
        Bs[row][c] = B[(r0 + row) * 256 + c];
    }
#pragma unroll
    for (int k2 = 0; k2 < 8; ++k2)
        masks[k2 * 512 + tid] = TBL.v[k2 * 512 + tid];
    __syncthreads();

    const int w = tid >> 6;  // wave id 0..7: m-range split
    const int t = tid & 63;  // thread owns outputs i = 4t+r

    float acc[2][3][4] = {};  // [row][prod][r]

#pragma unroll 2
    for (int gg = 0; gg < 8; ++gg) {
        const int g = (w << 3) | gg;  // this wave's m-group
        const unsigned long long mw = masks[(g << 6) | t];
        float av[2][4], bv[2][4];
#pragma unroll
        for (int row = 0; row < 2; ++row) {
            const float4 a4 = ((const float4*)As[row])[g ^ t];  // XOR-permuted
            const float4 b4 = ((const float4*)Bs[row])[g];      // broadcast
            av[row][0] = a4.x; av[row][1] = a4.y; av[row][2] = a4.z; av[row][3] = a4.w;
            bv[row][0] = b4.x; bv[row][1] = b4.y; bv[row][2] = b4.z; bv[row][3] = b4.w;
        }
        const unsigned lo = (unsigned)mw;
        const unsigned hi = (unsigned)(mw >> 32);
#pragma unroll
        for (int r = 0; r < 4; ++r) {
#pragma unroll
            for (int u = 0; u < 4; ++u) {
                const int q = u ^ r;          // m = 4g+q pairs with a-elem u
                const int pi = (r << 2) | q;  // static bit position
                const unsigned smask = ((unsigned)sbfe1(lo, pi)) & 0x80000000u;
                const unsigned wm = (unsigned)sbfe1(lo, 16 + pi);
                const unsigned im = (unsigned)sbfe1(hi, pi);
#pragma unroll
                for (int row = 0; row < 2; ++row) {
                    const float p = av[row][u] * bv[row][q];
                    const unsigned pu = __float_as_uint(p) ^ smask;
                    acc[row][0][r] += __uint_as_float(pu);
                    acc[row][1][r] += __uint_as_float(pu & wm);
                    acc[row][2][r] += __uint_as_float(pu & im);
                }
            }
        }
    }

    // Cross-wave reduction reusing the mask LDS (16 KB per pass):
    // red[w][row*256 + r*64 + t] holds acc for component comp = 4t+r.
    float* red = (float*)masks;
#pragma unroll
    for (int p = 0; p < 3; ++p) {
        __syncthreads();
#pragma unroll
        for (int row = 0; row < 2; ++row)
#pragma unroll
            for (int r = 0; r < 4; ++r)
                red[w * 512 + row * 256 + (r << 6) + t] = acc[row][p][r];
        __syncthreads();
        {
            const int row = tid >> 8;        // 0..1
            const int comp = tid & 255;
            const int swz = row * 256 + (comp >> 2) + ((comp & 3) << 6);
            float s = 0.f;
#pragma unroll
            for (int ww = 0; ww < 8; ++ww) s += red[ww * 512 + swz];
            out[p * 262144 + (r0 + row) * 256 + comp] = s;  // [3][1024][256]
        }
    }
}

extern "C" void kernel_launch(void* const* d_in, const int* in_sizes, int n_in,
                              void* d_out, int out_size, void* d_ws, size_t ws_size,
                              hipStream_t stream) {
    const float* A = (const float*)d_in[0];
    const float* B = (const float*)d_in[1];
    float* out = (float*)d_out;
    (void)d_ws; (void)ws_size;  // workspace deliberately unused

    clifford_main_kernel<<<512, 512, 0, stream>>>(A, B, out);
}

// Round 5
// 96.021 us; speedup vs baseline: 1.0105x; 1.0105x over previous
//
#include <hip/hip_runtime.h>
#include <cstdint>
#include <utility>

#ifndef __has_builtin
#define __has_builtin(x) 0
#endif

// Extract bit `off` of x and sign-extend: returns 0 or -1 (all-ones mask).
__device__ __forceinline__ int sbfe1(unsigned x, int off) {
#if __has_builtin(__builtin_amdgcn_sbfe)
    return __builtin_amdgcn_sbfe((int)x, off, 1);
#else
    return ((int)(x << (31 - off))) >> 31;
#endif
}

// ---------------------------------------------------------------------------
// Compile-time mask table, built in 64 per-g chunks so each constexpr
// evaluation stays far under clang's -fconstexpr-steps limit (1M).
//
// Word layout for (t, g): 16 pairs (r,q), pi = r*4+q.
//   bit pi    : sign of gp term (1 = negative)
//   bit 16+pi : wedge condition (m subset of i)
//   bit 32+pi : inner condition (m&i==0 or i subset of m)
// where i = 4t+r, m = 4g+q, j = m^i.
// ---------------------------------------------------------------------------
struct Row { unsigned long long v[64]; };

constexpr Row build_row(int g) {
    Row row{};
    for (int t = 0; t < 64; ++t) {
        unsigned long long word = 0ull;
        for (int r = 0; r < 4; ++r) {
            for (int q = 0; q < 4; ++q) {
                const int i = 4 * t + r;
                const int m = 4 * g + q;
                const int j = m ^ i;
                const int pi = r * 4 + q;
                int cnt = 0, pb = 0;  // pb = popc(m & ((1<<p)-1))
                for (int p = 0; p < 8; ++p) {
                    if ((j >> p) & 1) cnt += pb;
                    pb += (m >> p) & 1;
                }
                if (cnt & 1)                           word |= (1ull << pi);
                if ((m & ~i) == 0)                     word |= (1ull << (16 + pi));
                if (((m & i) == 0) || ((i & ~m) == 0)) word |= (1ull << (32 + pi));
            }
        }
        row.v[t] = word;
    }
    return row;
}

template <int G>
inline constexpr Row row_v = build_row(G);  // one constexpr eval per g (~60K steps)

struct MaskTbl { unsigned long long v[4096]; };

constexpr void copy_row(MaskTbl& tb, int g, const Row& r) {
    for (int t = 0; t < 64; ++t) tb.v[g * 64 + t] = r.v[t];
}

template <std::size_t... Gs>
constexpr MaskTbl gather(std::index_sequence<Gs...>) {
    MaskTbl tb{};
    ((copy_row(tb, (int)Gs, row_v<(int)Gs>)), ...);  // reads cached constants only
    return tb;
}

// 32 KB static device table — no workspace, no prep kernel. L2-resident.
__device__ constexpr MaskTbl TBL = gather(std::make_index_sequence<64>{});

// 4 rows per block, 256 blocks, 512 threads (the R2 structure — best
// measured; both the float2-pack and the 2-row/512-block occupancy split
// regressed). Inner loop reworked to FMA form: sign applied to the A
// operand (exact: (-a)b = -(ab)), wedge/inner zero-masks applied to the B
// operand (as*(b&0) = +-0, accumulator-neutral) -> 6 VALU ops per row-term
// instead of 7 (v_fmac fuses mul+add), -12.5% main-loop instructions.
__global__ __launch_bounds__(512) void clifford_main_kernel(
        const float* __restrict__ A, const float* __restrict__ B,
        float* __restrict__ out) {
    __shared__ float As[4][256];
    __shared__ float Bs[4][256];
    __shared__ unsigned long long masks[4096];  // 32 KB; reused as red[8][4][256]

    const int tid = threadIdx.x;   // 0..511
    const int r0 = blockIdx.x * 4; // rows r0..r0+3

    {
        const int row = tid >> 8;  // 0..1
        const int c = tid & 255;
        As[row][c]     = A[(r0 + row) * 256 + c];
        As[row + 2][c] = A[(r0 + row + 2) * 256 + c];
        Bs[row][c]     = B[(r0 + row) * 256 + c];
        Bs[row + 2][c] = B[(r0 + row + 2) * 256 + c];
    }
#pragma unroll
    for (int k2 = 0; k2 < 8; ++k2)
        masks[k2 * 512 + tid] = TBL.v[k2 * 512 + tid];
    __syncthreads();

    const int w = tid >> 6;  // wave id 0..7: m-range split
    const int t = tid & 63;  // thread owns outputs i = 4t+r

    float acc[4][3][4] = {};  // [row][prod][r]

#pragma unroll 2
    for (int gg = 0; gg < 8; ++gg) {
        const int g = (w << 3) | gg;  // this wave's m-group
        const unsigned long long mw = masks[(g << 6) | t];
        float av[4][4], bv[4][4];
#pragma unroll
        for (int row = 0; row < 4; ++row) {
            const float4 a4 = ((const float4*)As[row])[g ^ t];  // XOR-permuted
            const float4 b4 = ((const float4*)Bs[row])[g];      // broadcast
            av[row][0] = a4.x; av[row][1] = a4.y; av[row][2] = a4.z; av[row][3] = a4.w;
            bv[row][0] = b4.x; bv[row][1] = b4.y; bv[row][2] = b4.z; bv[row][3] = b4.w;
        }
        const unsigned lo = (unsigned)mw;
        const unsigned hi = (unsigned)(mw >> 32);
#pragma unroll
        for (int r = 0; r < 4; ++r) {
#pragma unroll
            for (int u = 0; u < 4; ++u) {
                const int q = u ^ r;          // m = 4g+q pairs with a-elem u
                const int pi = (r << 2) | q;  // static bit position
                const unsigned smask = ((unsigned)sbfe1(lo, pi)) & 0x80000000u;
                const unsigned wm = (unsigned)sbfe1(lo, 16 + pi);
                const unsigned im = (unsigned)sbfe1(hi, pi);
#pragma unroll
                for (int row = 0; row < 4; ++row) {
                    // Sign on A operand; zero-masks on B operand; FMA fuses.
                    const float as = __uint_as_float(__float_as_uint(av[row][u]) ^ smask);
                    const unsigned bu = __float_as_uint(bv[row][q]);
                    const float bw = __uint_as_float(bu & wm);
                    const float bi = __uint_as_float(bu & im);
                    acc[row][0][r] = __builtin_fmaf(as, bv[row][q], acc[row][0][r]);
                    acc[row][1][r] = __builtin_fmaf(as, bw, acc[row][1][r]);
                    acc[row][2][r] = __builtin_fmaf(as, bi, acc[row][2][r]);
                }
            }
        }
    }

    // Chunked cross-wave reduction reusing the mask LDS (32 KB per pass):
    // red[w][row][r*64 + t] holds acc for component comp = 4t+r.
    float* red = (float*)masks;
#pragma unroll
    for (int p = 0; p < 3; ++p) {
        __syncthreads();
#pragma unroll
        for (int row = 0; row < 4; ++row)
#pragma unroll
            for (int r = 0; r < 4; ++r)
                red[w * 1024 + row * 256 + (r << 6) + t] = acc[row][p][r];
        __syncthreads();
#pragma unroll
        for (int c = 0; c < 2; ++c) {
            const int idx = (c << 9) + tid;  // 0..1023
            const int row = idx >> 8;
            const int comp = idx & 255;
            const int swz = row * 256 + (comp >> 2) + ((comp & 3) << 6);
            float s = 0.f;
#pragma unroll
            for (int ww = 0; ww < 8; ++ww) s += red[ww * 1024 + swz];
            out[p * 262144 + (r0 + row) * 256 + comp] = s;  // [3][1024][256]
        }
    }
}

extern "C" void kernel_launch(void* const* d_in, const int* in_sizes, int n_in,
                              void* d_out, int out_size, void* d_ws, size_t ws_size,
                              hipStream_t stream) {
    const float* A = (const float*)d_in[0];
    const float* B = (const float*)d_in[1];
    float* out = (float*)d_out;
    (void)d_ws; (void)ws_size;  // workspace deliberately unused

    clifford_main_kernel<<<256, 512, 0, stream>>>(A, B, out);
}

// Round 6
// 91.830 us; speedup vs baseline: 1.0566x; 1.0456x over previous
//
#include <hip/hip_runtime.h>
#include <cstdint>
#include <utility>

#ifndef __has_builtin
#define __has_builtin(x) 0
#endif

// Extract bit `off` of x and sign-extend: returns 0 or -1 (all-ones mask).
__device__ __forceinline__ int sbfe1(unsigned x, int off) {
#if __has_builtin(__builtin_amdgcn_sbfe)
    return __builtin_amdgcn_sbfe((int)x, off, 1);
#else
    return ((int)(x << (31 - off))) >> 31;
#endif
}

// ---------------------------------------------------------------------------
// Compile-time mask table, built in 64 per-g chunks so each constexpr
// evaluation stays far under clang's -fconstexpr-steps limit (1M).
//
// Word layout for (t, g): 16 pairs (r,q), pi = r*4+q.
//   bit pi    : sign of gp term (1 = negative)
//   bit 16+pi : wedge condition (m subset of i)
//   bit 32+pi : inner condition (m&i==0 or i subset of m)
// where i = 4t+r, m = 4g+q, j = m^i.
// ---------------------------------------------------------------------------
struct Row { unsigned long long v[64]; };

constexpr Row build_row(int g) {
    Row row{};
    for (int t = 0; t < 64; ++t) {
        unsigned long long word = 0ull;
        for (int r = 0; r < 4; ++r) {
            for (int q = 0; q < 4; ++q) {
                const int i = 4 * t + r;
                const int m = 4 * g + q;
                const int j = m ^ i;
                const int pi = r * 4 + q;
                int cnt = 0, pb = 0;  // pb = popc(m & ((1<<p)-1))
                for (int p = 0; p < 8; ++p) {
                    if ((j >> p) & 1) cnt += pb;
                    pb += (m >> p) & 1;
                }
                if (cnt & 1)                           word |= (1ull << pi);
                if ((m & ~i) == 0)                     word |= (1ull << (16 + pi));
                if (((m & i) == 0) || ((i & ~m) == 0)) word |= (1ull << (32 + pi));
            }
        }
        row.v[t] = word;
    }
    return row;
}

template <int G>
inline constexpr Row row_v = build_row(G);  // one constexpr eval per g (~60K steps)

struct MaskTbl { unsigned long long v[4096]; };

constexpr void copy_row(MaskTbl& tb, int g, const Row& r) {
    for (int t = 0; t < 64; ++t) tb.v[g * 64 + t] = r.v[t];
}

template <std::size_t... Gs>
constexpr MaskTbl gather(std::index_sequence<Gs...>) {
    MaskTbl tb{};
    ((copy_row(tb, (int)Gs, row_v<(int)Gs>)), ...);  // reads cached constants only
    return tb;
}

// 32 KB static device table — no workspace, no prep kernel. L2-resident.
__device__ constexpr MaskTbl TBL = gather(std::make_index_sequence<64>{});

// 4 rows per block, 256 blocks, 512 threads — R2 structure + R2 scalar inner
// loop (best measured; float2-pack, occupancy-split, and FMA variants all
// regressed). Epilogue reworked: single fused reduction pass over a 96 KB
// scratch (union'd with the mask table; 104 KB LDS total), 2 barriers
// instead of 6, with a (t+16r)&63 rotation so the read phase is 2-way
// bank-aliased (free) instead of 4-way (1.58x).
__global__ __launch_bounds__(512) void clifford_main_kernel(
        const float* __restrict__ A, const float* __restrict__ B,
        float* __restrict__ out) {
    __shared__ float As[4][256];
    __shared__ float Bs[4][256];
    // 96 KB: first 32 KB doubles as the mask table (main loop), whole
    // buffer doubles as red[8][3][4][256] (epilogue).
    __shared__ unsigned long long shbuf[12288];
    unsigned long long* masks = shbuf;
    float* red = (float*)shbuf;

    const int tid = threadIdx.x;   // 0..511
    const int r0 = blockIdx.x * 4; // rows r0..r0+3

    {
        const int row = tid >> 8;  // 0..1
        const int c = tid & 255;
        As[row][c]     = A[(r0 + row) * 256 + c];
        As[row + 2][c] = A[(r0 + row + 2) * 256 + c];
        Bs[row][c]     = B[(r0 + row) * 256 + c];
        Bs[row + 2][c] = B[(r0 + row + 2) * 256 + c];
    }
#pragma unroll
    for (int k2 = 0; k2 < 8; ++k2)
        masks[k2 * 512 + tid] = TBL.v[k2 * 512 + tid];
    __syncthreads();

    const int w = tid >> 6;  // wave id 0..7: m-range split
    const int t = tid & 63;  // thread owns outputs i = 4t+r

    float acc[4][3][4] = {};  // [row][prod][r]

#pragma unroll 2
    for (int gg = 0; gg < 8; ++gg) {
        const int g = (w << 3) | gg;  // this wave's m-group
        const unsigned long long mw = masks[(g << 6) | t];
        float av[4][4], bv[4][4];
#pragma unroll
        for (int row = 0; row < 4; ++row) {
            const float4 a4 = ((const float4*)As[row])[g ^ t];  // XOR-permuted
            const float4 b4 = ((const float4*)Bs[row])[g];      // broadcast
            av[row][0] = a4.x; av[row][1] = a4.y; av[row][2] = a4.z; av[row][3] = a4.w;
            bv[row][0] = b4.x; bv[row][1] = b4.y; bv[row][2] = b4.z; bv[row][3] = b4.w;
        }
        const unsigned lo = (unsigned)mw;
        const unsigned hi = (unsigned)(mw >> 32);
#pragma unroll
        for (int r = 0; r < 4; ++r) {
#pragma unroll
            for (int u = 0; u < 4; ++u) {
                const int q = u ^ r;          // m = 4g+q pairs with a-elem u
                const int pi = (r << 2) | q;  // static bit position
                const unsigned smask = ((unsigned)sbfe1(lo, pi)) & 0x80000000u;
                const unsigned wm = (unsigned)sbfe1(lo, 16 + pi);
                const unsigned im = (unsigned)sbfe1(hi, pi);
#pragma unroll
                for (int row = 0; row < 4; ++row) {
                    const float p = av[row][u] * bv[row][q];
                    const unsigned pu = __float_as_uint(p) ^ smask;
                    acc[row][0][r] += __uint_as_float(pu);
                    acc[row][1][r] += __uint_as_float(pu & wm);
                    acc[row][2][r] += __uint_as_float(pu & im);
                }
            }
        }
    }

    // Fused single-pass cross-wave reduction.
    // Storage: red[w][p][row][(r<<6) + ((t+16r)&63)] — rotation keeps the
    // write phase conflict-free and the read phase at free 2-way aliasing.
    __syncthreads();  // masks no longer needed; safe to overwrite
#pragma unroll
    for (int row = 0; row < 4; ++row)
#pragma unroll
        for (int p = 0; p < 3; ++p)
#pragma unroll
            for (int r = 0; r < 4; ++r)
                red[w * 3072 + p * 1024 + row * 256 + (r << 6) +
                    ((t + (r << 4)) & 63)] = acc[row][p][r];
    __syncthreads();

#pragma unroll
    for (int c = 0; c < 6; ++c) {
        const int fidx = (c << 9) + tid;   // 0..3071 over 3 prods x 4 rows x 256
        const int p    = fidx >> 10;
        const int rowr = (fidx >> 8) & 3;
        const int comp = fidx & 255;
        const int r    = comp & 3;
        const int t2   = comp >> 2;        // comp = 4*t2 + r
        const int base = p * 1024 + rowr * 256 + (r << 6) + ((t2 + (r << 4)) & 63);
        float s = 0.f;
#pragma unroll
        for (int ww = 0; ww < 8; ++ww) s += red[ww * 3072 + base];
        out[p * 262144 + (r0 + rowr) * 256 + comp] = s;  // [3][1024][256]
    }
}

extern "C" void kernel_launch(void* const* d_in, const int* in_sizes, int n_in,
                              void* d_out, int out_size, void* d_ws, size_t ws_size,
                              hipStream_t stream) {
    const float* A = (const float*)d_in[0];
    const float* B = (const float*)d_in[1];
    float* out = (float*)d_out;
    (void)d_ws; (void)ws_size;  // workspace deliberately unused

    clifford_main_kernel<<<256, 512, 0, stream>>>(A, B, out);
}